// Round 1
// baseline (269.168 us; speedup 1.0000x reference)
//
#include <hip/hip_runtime.h>
#include <hip/hip_bf16.h>
#include <cstdint>

#define DEV static __device__ __forceinline__

typedef float        v4f __attribute__((ext_vector_type(4)));
typedef short        v8s __attribute__((ext_vector_type(8)));
typedef unsigned int v4u __attribute__((ext_vector_type(4)));

static constexpr int N_ENT = 100000;
static constexpr int BATCH = 4096;

DEV unsigned short f2bf(float f) {
    unsigned int u = __float_as_uint(f);
    u += 0x7fffu + ((u >> 16) & 1u);   // RNE
    return (unsigned short)(u >> 16);
}
DEV float bflo(unsigned int w) { return __uint_as_float(w << 16); }
DEV float bfhi(unsigned int w) { return __uint_as_float(w & 0xffff0000u); }

// ---------------- K0: tiny prep: R1 = rel @ W1[64:], W2 packed into MFMA B-frag layout
__global__ void k0_prep(const float* __restrict__ rel, const float* __restrict__ W1,
                        const float* __restrict__ W2,
                        float* __restrict__ R1, unsigned short* __restrict__ W2p)
{
    const int tid = threadIdx.x;
    for (int f = tid; f < 32 * 64; f += 256) {
        const int r = f >> 6, j = f & 63;
        float acc = 0.f;
        #pragma unroll 8
        for (int k = 0; k < 64; ++k)
            acc += rel[r * 64 + k] * W1[(64 + k) * 64 + j];
        R1[f] = acc;
    }
    // W2p[((kk*4+tn)*64 + l)*8 + i] = bf16( W2[(32kk + 8*(l>>4) + i)][16tn + (l&15)] )
    for (int f = tid; f < 4096; f += 256) {
        const int i = f & 7, l = (f >> 3) & 63;
        const int tn = (f >> 9) & 3, kk = f >> 11;
        const int k = 32 * kk + 8 * (l >> 4) + i;
        const int j = 16 * tn + (l & 15);
        W2p[f] = f2bf(W2[k * 64 + j]);
    }
}

// ---------------- K1: E1[e][j] = sum_k emb[e][k] * W1[k][j]  (bf16 out)
__global__ void __launch_bounds__(256) k1_e1(const float* __restrict__ emb,
                                             const float* __restrict__ W1,
                                             unsigned short* __restrict__ E1)
{
    const int lane = threadIdx.x & 63;
    const int gwave = (blockIdx.x * blockDim.x + threadIdx.x) >> 6;
    const int nwave = (gridDim.x * blockDim.x) >> 6;
    float w1c[64];
    #pragma unroll
    for (int k = 0; k < 64; ++k) w1c[k] = W1[k * 64 + lane];   // column `lane`
    for (int e = gwave; e < N_ENT; e += nwave) {
        const float rv = emb[e * 64 + lane];
        float a0 = 0.f, a1 = 0.f, a2 = 0.f, a3 = 0.f;
        #pragma unroll
        for (int k = 0; k < 16; ++k) {
            a0 += __shfl(rv, k)      * w1c[k];
            a1 += __shfl(rv, k + 16) * w1c[k + 16];
            a2 += __shfl(rv, k + 32) * w1c[k + 32];
            a3 += __shfl(rv, k + 48) * w1c[k + 48];
        }
        E1[e * 64 + lane] = f2bf((a0 + a1) + (a2 + a3));
    }
}

// ---------------- K2: per (b, combo) wave: attention over T=64 triples
__global__ void __launch_bounds__(256) k2_att(
    const int* __restrict__ user_h, const int* __restrict__ user_r, const int* __restrict__ user_t,
    const int* __restrict__ item_h, const int* __restrict__ item_r, const int* __restrict__ item_t,
    const float* __restrict__ emb, const unsigned short* __restrict__ E1,
    const float* __restrict__ R1, const unsigned short* __restrict__ W2p,
    const float* __restrict__ W3, float* __restrict__ att)
{
    const int lane  = threadIdx.x & 63;
    const int b     = blockIdx.x;
    const int combo = threadIdx.x >> 6;        // 0:uL0 1:uL1 2:iL0 3:iL1
    const int layer = combo & 1;
    const int* Hp; const int* Rp; const int* Tp;
    if (combo < 2) { Hp = user_h; Rp = user_r; Tp = user_t; }
    else           { Hp = item_h; Rp = item_r; Tp = item_t; }
    const int base = (layer * BATCH + b) * 64;

    const int q = lane & 15, g = lane >> 4;

    int hidx[4], ridx[4];
    #pragma unroll
    for (int tm = 0; tm < 4; ++tm) {
        hidx[tm] = Hp[base + 16 * tm + q];
        ridx[tm] = Rp[base + 16 * tm + q];
    }
    const int tv = Tp[base + lane];

    v4f acc[4][4];
    #pragma unroll
    for (int tm = 0; tm < 4; ++tm)
        #pragma unroll
        for (int tn = 0; tn < 4; ++tn)
            acc[tm][tn] = (v4f){0.f, 0.f, 0.f, 0.f};

    #pragma unroll
    for (int kk = 0; kk < 2; ++kk) {
        v8s bfr[4];
        #pragma unroll
        for (int tn = 0; tn < 4; ++tn)
            bfr[tn] = *(const v8s*)(W2p + ((kk * 4 + tn) * 64 + lane) * 8);
        #pragma unroll
        for (int tm = 0; tm < 4; ++tm) {
            const unsigned short* e1p = E1 + hidx[tm] * 64 + 32 * kk + 8 * g;
            const float*          r1p = R1 + ridx[tm] * 64 + 32 * kk + 8 * g;
            const v4u ev = *(const v4u*)e1p;
            const v4f ra = *(const v4f*)r1p;
            const v4f rb = *(const v4f*)(r1p + 4);
            float v0 = fmaxf(bflo(ev[0]) + ra[0], 0.f);
            float v1 = fmaxf(bfhi(ev[0]) + ra[1], 0.f);
            float v2 = fmaxf(bflo(ev[1]) + ra[2], 0.f);
            float v3 = fmaxf(bfhi(ev[1]) + ra[3], 0.f);
            float v4 = fmaxf(bflo(ev[2]) + rb[0], 0.f);
            float v5 = fmaxf(bfhi(ev[2]) + rb[1], 0.f);
            float v6 = fmaxf(bflo(ev[3]) + rb[2], 0.f);
            float v7 = fmaxf(bfhi(ev[3]) + rb[3], 0.f);
            v8s af;
            af[0] = (short)f2bf(v0); af[1] = (short)f2bf(v1);
            af[2] = (short)f2bf(v2); af[3] = (short)f2bf(v3);
            af[4] = (short)f2bf(v4); af[5] = (short)f2bf(v5);
            af[6] = (short)f2bf(v6); af[7] = (short)f2bf(v7);
            #pragma unroll
            for (int tn = 0; tn < 4; ++tn)
                acc[tm][tn] = __builtin_amdgcn_mfma_f32_16x16x32_bf16(af, bfr[tn], acc[tm][tn], 0, 0, 0);
        }
    }

    // logits: p[tm][i] = sum_j relu(a2[t][j]) * W3[j], t = 16tm + 4g + i, j = 16tn + q
    float w3v[4];
    #pragma unroll
    for (int tn = 0; tn < 4; ++tn) w3v[tn] = W3[16 * tn + q];

    float p[4][4];
    #pragma unroll
    for (int tm = 0; tm < 4; ++tm)
        #pragma unroll
        for (int i = 0; i < 4; ++i) {
            float s = 0.f;
            #pragma unroll
            for (int tn = 0; tn < 4; ++tn)
                s += fmaxf(acc[tm][tn][i], 0.f) * w3v[tn];
            p[tm][i] = s;
        }
    #pragma unroll
    for (int m = 1; m <= 8; m <<= 1)
        #pragma unroll
        for (int tm = 0; tm < 4; ++tm)
            #pragma unroll
            for (int i = 0; i < 4; ++i)
                p[tm][i] += __shfl_xor(p[tm][i], m);

    // sigmoid -> exp (softmax numerator; logits in [0,1] so no max-shift needed)
    float ee[4][4];
    float sloc = 0.f;
    #pragma unroll
    for (int tm = 0; tm < 4; ++tm)
        #pragma unroll
        for (int i = 0; i < 4; ++i) {
            const float sg = 1.f / (1.f + __expf(-p[tm][i]));
            const float ex = __expf(sg);
            ee[tm][i] = ex;
            sloc += ex;
        }
    sloc += __shfl_xor(sloc, 16);
    sloc += __shfl_xor(sloc, 32);
    const float rS = 1.f / sloc;

    // weighted sum of t-embeddings: lane = output dim j
    float accj = 0.f;
    #pragma unroll
    for (int t = 0; t < 64; ++t) {
        const int tm = t >> 4, gg = (t >> 2) & 3, i = t & 3;
        const float e_t = __shfl(ee[tm][i], gg * 16);
        const int   ti  = __shfl(tv, t);
        accj += e_t * emb[ti * 64 + lane];
    }
    att[(combo * BATCH + b) * 64 + lane] = accj * rS;
}

// ---------------- K3: combine + means + dot + sigmoid
__global__ void __launch_bounds__(256) k3_final(
    const int* __restrict__ items, const int* __restrict__ user_h0, const int* __restrict__ item_h0,
    const float* __restrict__ emb, const float* __restrict__ att, float* __restrict__ out)
{
    const int lane = threadIdx.x & 63;
    const int b = blockIdx.x * 4 + (threadIdx.x >> 6);
    const int it = items[b];
    float ev = emb[it * 64 + lane]
             + att[(2 * BATCH + b) * 64 + lane] + att[(3 * BATCH + b) * 64 + lane];
    float eu = att[(0 * BATCH + b) * 64 + lane] + att[(1 * BATCH + b) * 64 + lane];
    const int uv = user_h0[b * 64 + lane];
    const int iv = item_h0[b * 64 + lane];
    float um = 0.f, im = 0.f;
    #pragma unroll 8
    for (int t = 0; t < 64; ++t) {
        const int uh = __shfl(uv, t);
        const int ih = __shfl(iv, t);
        um += emb[uh * 64 + lane];
        im += emb[ih * 64 + lane];
    }
    eu += um * (1.f / 64.f);
    ev += im * (1.f / 64.f);
    float d = eu * ev;
    #pragma unroll
    for (int m = 1; m <= 32; m <<= 1) d += __shfl_xor(d, m);
    if (lane == 0) out[b] = 1.f / (1.f + __expf(-d));
}

extern "C" void kernel_launch(void* const* d_in, const int* in_sizes, int n_in,
                              void* d_out, int out_size, void* d_ws, size_t ws_size,
                              hipStream_t stream)
{
    const int*   items  = (const int*)d_in[0];
    const int*   user_h = (const int*)d_in[1];
    const int*   user_r = (const int*)d_in[2];
    const int*   user_t = (const int*)d_in[3];
    const int*   item_h = (const int*)d_in[4];
    const int*   item_r = (const int*)d_in[5];
    const int*   item_t = (const int*)d_in[6];
    const float* emb    = (const float*)d_in[7];
    const float* rel    = (const float*)d_in[8];
    const float* W1     = (const float*)d_in[9];
    const float* W2     = (const float*)d_in[10];
    const float* W3     = (const float*)d_in[11];
    float* out = (float*)d_out;

    char* ws = (char*)d_ws;
    float*          att = (float*)ws;                                   // 4*4096*64*4 = 4 MB
    unsigned short* E1  = (unsigned short*)(ws + (4 << 20));            // 100000*64*2 = 12.8 MB
    float*          R1  = (float*)(ws + (4 << 20) + N_ENT * 64 * 2);    // 8 KB
    unsigned short* W2p = (unsigned short*)(ws + (4 << 20) + N_ENT * 64 * 2 + 32 * 64 * 4); // 8 KB

    hipLaunchKernelGGL(k0_prep, dim3(1), dim3(256), 0, stream, rel, W1, W2, R1, W2p);
    hipLaunchKernelGGL(k1_e1, dim3(512), dim3(256), 0, stream, emb, W1, E1);
    hipLaunchKernelGGL(k2_att, dim3(BATCH), dim3(256), 0, stream,
                       user_h, user_r, user_t, item_h, item_r, item_t,
                       emb, E1, R1, W2p, W3, att);
    hipLaunchKernelGGL(k3_final, dim3(BATCH / 4), dim3(256), 0, stream,
                       items, user_h, item_h, emb, att, out);
}

// Round 2
// 172.240 us; speedup vs baseline: 1.5628x; 1.5628x over previous
//
#include <hip/hip_runtime.h>
#include <hip/hip_bf16.h>
#include <cstdint>

#define DEV static __device__ __forceinline__

typedef float        v4f __attribute__((ext_vector_type(4)));
typedef short        v8s __attribute__((ext_vector_type(8)));
typedef unsigned int v4u __attribute__((ext_vector_type(4)));

static constexpr int N_ENT = 100000;
static constexpr int BATCH = 4096;

DEV unsigned short f2bf(float f) {
    unsigned int u = __float_as_uint(f);
    u += 0x7fffu + ((u >> 16) & 1u);   // RNE
    return (unsigned short)(u >> 16);
}
DEV float bflo(unsigned int w) { return __uint_as_float(w << 16); }
DEV float bfhi(unsigned int w) { return __uint_as_float(w & 0xffff0000u); }

DEV void acc_bf8(float* a8, float w, const unsigned short* p) {
    const v4u ev = *(const v4u*)p;
    a8[0] += w * bflo(ev[0]); a8[1] += w * bfhi(ev[0]);
    a8[2] += w * bflo(ev[1]); a8[3] += w * bfhi(ev[1]);
    a8[4] += w * bflo(ev[2]); a8[5] += w * bfhi(ev[2]);
    a8[6] += w * bflo(ev[3]); a8[7] += w * bfhi(ev[3]);
}

// ---------------- K0: R1 = rel @ W1[64:], W2 packed into MFMA B-frag layout (24 blocks)
__global__ void k0_prep(const float* __restrict__ rel, const float* __restrict__ W1,
                        const float* __restrict__ W2,
                        float* __restrict__ R1, unsigned short* __restrict__ W2p)
{
    const int gid = blockIdx.x * 256 + threadIdx.x;
    if (gid < 2048) {
        const int r = gid >> 6, j = gid & 63;
        float acc = 0.f;
        #pragma unroll 8
        for (int k = 0; k < 64; ++k)
            acc += rel[r * 64 + k] * W1[(64 + k) * 64 + j];
        R1[gid] = acc;
    } else if (gid < 2048 + 4096) {
        // W2p[((kk*4+tn)*64 + l)*8 + i] = bf16( W2[(32kk + 8*(l>>4) + i)][16tn + (l&15)] )
        const int f = gid - 2048;
        const int i = f & 7, l = (f >> 3) & 63;
        const int tn = (f >> 9) & 3, kk = f >> 11;
        const int k = 32 * kk + 8 * (l >> 4) + i;
        const int j = 16 * tn + (l & 15);
        W2p[f] = f2bf(W2[k * 64 + j]);
    }
}

// ---------------- K1: E1[e] = bf16(emb[e] @ W1[:64]);  E0[e] = bf16(emb[e])
__global__ void __launch_bounds__(256) k1_e1(const float* __restrict__ emb,
                                             const float* __restrict__ W1,
                                             unsigned short* __restrict__ E1,
                                             unsigned short* __restrict__ E0)
{
    const int lane = threadIdx.x & 63;
    const int gwave = (blockIdx.x * blockDim.x + threadIdx.x) >> 6;
    const int nwave = (gridDim.x * blockDim.x) >> 6;
    float w1c[64];
    #pragma unroll
    for (int k = 0; k < 64; ++k) w1c[k] = W1[k * 64 + lane];   // column `lane`
    for (int e = gwave; e < N_ENT; e += nwave) {
        const float rv = emb[e * 64 + lane];
        float a0 = 0.f, a1 = 0.f, a2 = 0.f, a3 = 0.f;
        #pragma unroll
        for (int k = 0; k < 16; ++k) {
            a0 += __shfl(rv, k)      * w1c[k];
            a1 += __shfl(rv, k + 16) * w1c[k + 16];
            a2 += __shfl(rv, k + 32) * w1c[k + 32];
            a3 += __shfl(rv, k + 48) * w1c[k + 48];
        }
        E0[e * 64 + lane] = f2bf(rv);
        E1[e * 64 + lane] = f2bf((a0 + a1) + (a2 + a3));
    }
}

// ---------------- K2: fused attention (4 combos) + means + dot + sigmoid, one block per b
__global__ void __launch_bounds__(256) k2_fused(
    const int* __restrict__ items,
    const int* __restrict__ user_h, const int* __restrict__ user_r, const int* __restrict__ user_t,
    const int* __restrict__ item_h, const int* __restrict__ item_r, const int* __restrict__ item_t,
    const float* __restrict__ emb, const unsigned short* __restrict__ E0,
    const unsigned short* __restrict__ E1,
    const float* __restrict__ R1, const unsigned short* __restrict__ W2p,
    const float* __restrict__ W3, float* __restrict__ out)
{
    __shared__ float ws_w[4][64];   // softmax weights (incl 1/S)
    __shared__ int   ws_t[4][64];   // t indices
    __shared__ int   ws_h[2][64];   // hop-0 h indices (user/item)
    __shared__ float att_s[4][64];  // per-combo attention output
    __shared__ float mp[4][64];     // per-wave mean partials

    const int lane  = threadIdx.x & 63;
    const int b     = blockIdx.x;
    const int combo = threadIdx.x >> 6;        // 0:uL0 1:uL1 2:iL0 3:iL1
    const int layer = combo & 1;
    const int* Hp; const int* Rp; const int* Tp;
    if (combo < 2) { Hp = user_h; Rp = user_r; Tp = user_t; }
    else           { Hp = item_h; Rp = item_r; Tp = item_t; }
    const int base = (layer * BATCH + b) * 64;

    const int q = lane & 15, g = lane >> 4;

    int hidx[4], ridx[4];
    #pragma unroll
    for (int tm = 0; tm < 4; ++tm) {
        hidx[tm] = Hp[base + 16 * tm + q];
        ridx[tm] = Rp[base + 16 * tm + q];
    }
    const int tv = Tp[base + lane];

    v4f acc[4][4];
    #pragma unroll
    for (int tm = 0; tm < 4; ++tm)
        #pragma unroll
        for (int tn = 0; tn < 4; ++tn)
            acc[tm][tn] = (v4f){0.f, 0.f, 0.f, 0.f};

    #pragma unroll
    for (int kk = 0; kk < 2; ++kk) {
        v8s bfr[4];
        #pragma unroll
        for (int tn = 0; tn < 4; ++tn)
            bfr[tn] = *(const v8s*)(W2p + ((kk * 4 + tn) * 64 + lane) * 8);
        #pragma unroll
        for (int tm = 0; tm < 4; ++tm) {
            const unsigned short* e1p = E1 + hidx[tm] * 64 + 32 * kk + 8 * g;
            const float*          r1p = R1 + ridx[tm] * 64 + 32 * kk + 8 * g;
            const v4u ev = *(const v4u*)e1p;
            const v4f ra = *(const v4f*)r1p;
            const v4f rb = *(const v4f*)(r1p + 4);
            float v0 = fmaxf(bflo(ev[0]) + ra[0], 0.f);
            float v1 = fmaxf(bfhi(ev[0]) + ra[1], 0.f);
            float v2 = fmaxf(bflo(ev[1]) + ra[2], 0.f);
            float v3 = fmaxf(bfhi(ev[1]) + ra[3], 0.f);
            float v4 = fmaxf(bflo(ev[2]) + rb[0], 0.f);
            float v5 = fmaxf(bfhi(ev[2]) + rb[1], 0.f);
            float v6 = fmaxf(bflo(ev[3]) + rb[2], 0.f);
            float v7 = fmaxf(bfhi(ev[3]) + rb[3], 0.f);
            v8s af;
            af[0] = (short)f2bf(v0); af[1] = (short)f2bf(v1);
            af[2] = (short)f2bf(v2); af[3] = (short)f2bf(v3);
            af[4] = (short)f2bf(v4); af[5] = (short)f2bf(v5);
            af[6] = (short)f2bf(v6); af[7] = (short)f2bf(v7);
            #pragma unroll
            for (int tn = 0; tn < 4; ++tn)
                acc[tm][tn] = __builtin_amdgcn_mfma_f32_16x16x32_bf16(af, bfr[tn], acc[tm][tn], 0, 0, 0);
        }
    }

    // logits: p[tm][i] = sum_j relu(a2[t][j]) * W3[j], t = 16tm + 4g + i, j = 16tn + q
    float w3v[4];
    #pragma unroll
    for (int tn = 0; tn < 4; ++tn) w3v[tn] = W3[16 * tn + q];

    float p[4][4];
    #pragma unroll
    for (int tm = 0; tm < 4; ++tm)
        #pragma unroll
        for (int i = 0; i < 4; ++i) {
            float s = 0.f;
            #pragma unroll
            for (int tn = 0; tn < 4; ++tn)
                s += fmaxf(acc[tm][tn][i], 0.f) * w3v[tn];
            p[tm][i] = s;
        }
    #pragma unroll
    for (int m = 1; m <= 8; m <<= 1)
        #pragma unroll
        for (int tm = 0; tm < 4; ++tm)
            #pragma unroll
            for (int i = 0; i < 4; ++i)
                p[tm][i] += __shfl_xor(p[tm][i], m);

    // sigmoid -> exp (softmax numerator; logits in [0,1] so no max-shift needed)
    float ee[4][4];
    float sloc = 0.f;
    #pragma unroll
    for (int tm = 0; tm < 4; ++tm)
        #pragma unroll
        for (int i = 0; i < 4; ++i) {
            const float sg = 1.f / (1.f + __expf(-p[tm][i]));
            const float ex = __expf(sg);
            ee[tm][i] = ex;
            sloc += ex;
        }
    sloc += __shfl_xor(sloc, 16);
    sloc += __shfl_xor(sloc, 32);
    const float rS = 1.f / sloc;

    // stage weights / indices to LDS
    if (q == 0) {
        #pragma unroll
        for (int tm = 0; tm < 4; ++tm)
            #pragma unroll
            for (int i = 0; i < 4; ++i)
                ws_w[combo][16 * tm + 4 * g + i] = ee[tm][i] * rS;
    }
    ws_t[combo][lane] = tv;
    if (layer == 0 && g == 0) {
        #pragma unroll
        for (int tm = 0; tm < 4; ++tm)
            ws_h[combo >> 1][16 * tm + q] = hidx[tm];
    }
    __syncthreads();

    // vectorized weighted t-sum (8 rows/iter) + hop-0 means (interleaved for ILP)
    const int sub = lane & 7, grp = lane >> 3;
    const int side = combo >> 1, half = combo & 1;
    float a8[8], m8[8];
    #pragma unroll
    for (int k = 0; k < 8; ++k) { a8[k] = 0.f; m8[k] = 0.f; }
    #pragma unroll
    for (int it = 0; it < 8; ++it) {
        const int r = 8 * it + grp;
        const float w = ws_w[combo][r];
        const int  ti = ws_t[combo][r];
        acc_bf8(a8, w, E0 + ti * 64 + sub * 8);
    }
    #pragma unroll
    for (int it = 0; it < 4; ++it) {
        const int r = 32 * half + 8 * it + grp;
        const int idx = ws_h[side][r];
        acc_bf8(m8, 1.f, E0 + idx * 64 + sub * 8);
    }
    #pragma unroll
    for (int m = 8; m <= 32; m <<= 1)
        #pragma unroll
        for (int k = 0; k < 8; ++k) {
            a8[k] += __shfl_xor(a8[k], m);
            m8[k] += __shfl_xor(m8[k], m);
        }
    if (lane < 8) {
        #pragma unroll
        for (int k = 0; k < 8; ++k) {
            att_s[combo][lane * 8 + k] = a8[k];
            mp[combo][lane * 8 + k]    = m8[k];
        }
    }
    __syncthreads();

    // final combine + dot + sigmoid (one wave)
    if (threadIdx.x < 64) {
        const int j = lane;
        const float eu = att_s[0][j] + att_s[1][j] + (mp[0][j] + mp[1][j]) * (1.f / 64.f);
        const float ev = emb[items[b] * 64 + j] + att_s[2][j] + att_s[3][j]
                       + (mp[2][j] + mp[3][j]) * (1.f / 64.f);
        float d = eu * ev;
        #pragma unroll
        for (int m = 1; m <= 32; m <<= 1) d += __shfl_xor(d, m);
        if (lane == 0) out[b] = 1.f / (1.f + __expf(-d));
    }
}

extern "C" void kernel_launch(void* const* d_in, const int* in_sizes, int n_in,
                              void* d_out, int out_size, void* d_ws, size_t ws_size,
                              hipStream_t stream)
{
    const int*   items  = (const int*)d_in[0];
    const int*   user_h = (const int*)d_in[1];
    const int*   user_r = (const int*)d_in[2];
    const int*   user_t = (const int*)d_in[3];
    const int*   item_h = (const int*)d_in[4];
    const int*   item_r = (const int*)d_in[5];
    const int*   item_t = (const int*)d_in[6];
    const float* emb    = (const float*)d_in[7];
    const float* rel    = (const float*)d_in[8];
    const float* W1     = (const float*)d_in[9];
    const float* W2     = (const float*)d_in[10];
    const float* W3     = (const float*)d_in[11];
    float* out = (float*)d_out;

    char* ws = (char*)d_ws;
    const size_t tb = (size_t)N_ENT * 64 * 2;           // 12.8 MB per table
    unsigned short* E0  = (unsigned short*)ws;
    unsigned short* E1  = (unsigned short*)(ws + tb);
    float*          R1  = (float*)(ws + 2 * tb);
    unsigned short* W2p = (unsigned short*)(ws + 2 * tb + 32 * 64 * 4);

    hipLaunchKernelGGL(k0_prep, dim3(24), dim3(256), 0, stream, rel, W1, W2, R1, W2p);
    hipLaunchKernelGGL(k1_e1, dim3(512), dim3(256), 0, stream, emb, W1, E1, E0);
    hipLaunchKernelGGL(k2_fused, dim3(BATCH), dim3(256), 0, stream,
                       items, user_h, user_r, user_t, item_h, item_r, item_t,
                       emb, E0, E1, R1, W2p, W3, out);
}

// Round 3
// 76.966 us; speedup vs baseline: 3.4972x; 2.2379x over previous
//
#include <hip/hip_runtime.h>
#include <hip/hip_bf16.h>
#include <cstdint>

#define DEV static __device__ __forceinline__

typedef float        v4f __attribute__((ext_vector_type(4)));
typedef short        v8s __attribute__((ext_vector_type(8)));
typedef unsigned int v4u __attribute__((ext_vector_type(4)));

static constexpr int N_ENT = 100000;
static constexpr int BATCH = 4096;

DEV unsigned short f2bf(float f) {
    unsigned int u = __float_as_uint(f);
    u += 0x7fffu + ((u >> 16) & 1u);   // RNE
    return (unsigned short)(u >> 16);
}
DEV float bflo(unsigned int w) { return __uint_as_float(w << 16); }
DEV float bfhi(unsigned int w) { return __uint_as_float(w & 0xffff0000u); }

// ---------------- K0: R1b = bf16(rel @ W1[64:]); W2p/W1p packed into MFMA B-frag layout
__global__ void k0_prep(const float* __restrict__ rel, const float* __restrict__ W1,
                        const float* __restrict__ W2,
                        unsigned short* __restrict__ R1b, unsigned short* __restrict__ W2p,
                        unsigned short* __restrict__ W1p)
{
    const int gid = blockIdx.x * 256 + threadIdx.x;
    if (gid < 2048) {
        const int r = gid >> 6, j = gid & 63;
        float acc = 0.f;
        #pragma unroll 8
        for (int k = 0; k < 64; ++k)
            acc += rel[r * 64 + k] * W1[(64 + k) * 64 + j];
        R1b[gid] = f2bf(acc);
    } else if (gid < 2048 + 4096) {
        // Wp[((kk*4+tn)*64 + l)*8 + i] = bf16( W[(32kk + 8*(l>>4) + i)][16tn + (l&15)] )
        const int f = gid - 2048;
        const int i = f & 7, l = (f >> 3) & 63;
        const int tn = (f >> 9) & 3, kk = f >> 11;
        W2p[f] = f2bf(W2[(32 * kk + 8 * (l >> 4) + i) * 64 + 16 * tn + (l & 15)]);
    } else if (gid < 2048 + 8192) {
        const int f = gid - 6144;
        const int i = f & 7, l = (f >> 3) & 63;
        const int tn = (f >> 9) & 3, kk = f >> 11;
        W1p[f] = f2bf(W1[(32 * kk + 8 * (l >> 4) + i) * 64 + 16 * tn + (l & 15)]);
    }
}

// ---------------- K1: MFMA GEMM: E1 = bf16(emb @ W1[:64]); E0 = bf16(emb). 16 rows/wave.
__global__ void __launch_bounds__(256) k1_e1(const float* __restrict__ emb,
                                             const unsigned short* __restrict__ W1p,
                                             unsigned short* __restrict__ E1,
                                             unsigned short* __restrict__ E0)
{
    const int lane = threadIdx.x & 63;
    const int q = lane & 15, g = lane >> 4;
    const int wid = blockIdx.x * 4 + (threadIdx.x >> 6);
    const int e0 = wid * 16;
    if (e0 >= N_ENT) return;

    v8s af[2];
    #pragma unroll
    for (int kk = 0; kk < 2; ++kk) {
        const float* p = emb + (size_t)(e0 + q) * 64 + 32 * kk + 8 * g;
        const v4f x = *(const v4f*)p;
        const v4f y = *(const v4f*)(p + 4);
        v8s a;
        a[0] = (short)f2bf(x[0]); a[1] = (short)f2bf(x[1]);
        a[2] = (short)f2bf(x[2]); a[3] = (short)f2bf(x[3]);
        a[4] = (short)f2bf(y[0]); a[5] = (short)f2bf(y[1]);
        a[6] = (short)f2bf(y[2]); a[7] = (short)f2bf(y[3]);
        af[kk] = a;
        v4u pk;
        pk[0] = (unsigned short)a[0] | ((unsigned)(unsigned short)a[1] << 16);
        pk[1] = (unsigned short)a[2] | ((unsigned)(unsigned short)a[3] << 16);
        pk[2] = (unsigned short)a[4] | ((unsigned)(unsigned short)a[5] << 16);
        pk[3] = (unsigned short)a[6] | ((unsigned)(unsigned short)a[7] << 16);
        *(v4u*)(E0 + (size_t)(e0 + q) * 64 + 32 * kk + 8 * g) = pk;
    }

    v4f acc[4];
    #pragma unroll
    for (int tn = 0; tn < 4; ++tn) acc[tn] = (v4f){0.f, 0.f, 0.f, 0.f};
    #pragma unroll
    for (int kk = 0; kk < 2; ++kk)
        #pragma unroll
        for (int tn = 0; tn < 4; ++tn) {
            const v8s bfr = *(const v8s*)(W1p + ((kk * 4 + tn) * 64 + lane) * 8);
            acc[tn] = __builtin_amdgcn_mfma_f32_16x16x32_bf16(af[kk], bfr, acc[tn], 0, 0, 0);
        }
    #pragma unroll
    for (int tn = 0; tn < 4; ++tn)
        #pragma unroll
        for (int i = 0; i < 4; ++i)
            E1[(size_t)(e0 + 4 * g + i) * 64 + 16 * tn + q] = f2bf(acc[tn][i]);
}

// ---------------- K2: fused attention + means + dot + sigmoid; all gathers issued up front
__global__ void __launch_bounds__(256, 2) k2_fused(
    const int* __restrict__ items,
    const int* __restrict__ user_h, const int* __restrict__ user_r, const int* __restrict__ user_t,
    const int* __restrict__ item_h, const int* __restrict__ item_r, const int* __restrict__ item_t,
    const float* __restrict__ emb, const unsigned short* __restrict__ E0,
    const unsigned short* __restrict__ E1,
    const unsigned short* __restrict__ R1b, const unsigned short* __restrict__ W2p,
    const float* __restrict__ W3, float* __restrict__ out)
{
    __shared__ float ws_w[4][64];   // softmax weights (incl 1/S)
    __shared__ float att_s[4][64];  // per-combo attention output
    __shared__ float mp[4][64];     // per-wave mean partials

    const int lane  = threadIdx.x & 63;
    const int b     = blockIdx.x;
    const int combo = threadIdx.x >> 6;        // 0:uL0 1:uL1 2:iL0 3:iL1
    const int layer = combo & 1;
    const int side  = combo >> 1, half = combo & 1;
    const int* Hp; const int* Rp; const int* Tp;
    if (combo < 2) { Hp = user_h; Rp = user_r; Tp = user_t; }
    else           { Hp = item_h; Rp = item_r; Tp = item_t; }
    const int base = (layer * BATCH + b) * 64;
    const int* H0p = (side ? item_h : user_h) + b * 64;   // layer-0 heads for mean

    const int q = lane & 15, g = lane >> 4;
    const int sub = lane & 7, grp = lane >> 3;

    // ---- indices
    int hidx[4], ridx[4];
    #pragma unroll
    for (int tm = 0; tm < 4; ++tm) {
        hidx[tm] = Hp[base + 16 * tm + q];
        ridx[tm] = Rp[base + 16 * tm + q];
    }
    const int tv = Tp[base + lane];
    int midx[4];
    #pragma unroll
    for (int it = 0; it < 4; ++it) midx[it] = H0p[32 * half + 8 * it + grp];

    // ---- issue ALL gathers up front (register prefetch, max MLP)
    v4u ev[4][2], rv[4][2];
    #pragma unroll
    for (int tm = 0; tm < 4; ++tm)
        #pragma unroll
        for (int kk = 0; kk < 2; ++kk) {
            ev[tm][kk] = *(const v4u*)(E1  + (size_t)hidx[tm] * 64 + 32 * kk + 8 * g);
            rv[tm][kk] = *(const v4u*)(R1b + (size_t)ridx[tm] * 64 + 32 * kk + 8 * g);
        }
    v4u e0v[8];
    #pragma unroll
    for (int it = 0; it < 8; ++it) {
        const int tr = __shfl(tv, 8 * it + grp);
        e0v[it] = *(const v4u*)(E0 + (size_t)tr * 64 + sub * 8);
    }
    v4u m0v[4];
    #pragma unroll
    for (int it = 0; it < 4; ++it)
        m0v[it] = *(const v4u*)(E0 + (size_t)midx[it] * 64 + sub * 8);

    float w3v[4];
    #pragma unroll
    for (int tn = 0; tn < 4; ++tn) w3v[tn] = W3[16 * tn + q];

    // ---- MFMA: a2 = relu(relu(E1h + R1r) @ W2); logits p
    float p[4][4];
    #pragma unroll
    for (int tm = 0; tm < 4; ++tm) {
        v4f a4[4];
        #pragma unroll
        for (int tn = 0; tn < 4; ++tn) a4[tn] = (v4f){0.f, 0.f, 0.f, 0.f};
        #pragma unroll
        for (int kk = 0; kk < 2; ++kk) {
            v8s af;
            #pragma unroll
            for (int w = 0; w < 4; ++w) {
                const unsigned int e = ev[tm][kk][w], r = rv[tm][kk][w];
                af[2 * w]     = (short)f2bf(fmaxf(bflo(e) + bflo(r), 0.f));
                af[2 * w + 1] = (short)f2bf(fmaxf(bfhi(e) + bfhi(r), 0.f));
            }
            #pragma unroll
            for (int tn = 0; tn < 4; ++tn) {
                const v8s bfr = *(const v8s*)(W2p + ((kk * 4 + tn) * 64 + lane) * 8);
                a4[tn] = __builtin_amdgcn_mfma_f32_16x16x32_bf16(af, bfr, a4[tn], 0, 0, 0);
            }
        }
        #pragma unroll
        for (int i = 0; i < 4; ++i) {
            float s = 0.f;
            #pragma unroll
            for (int tn = 0; tn < 4; ++tn)
                s += fmaxf(a4[tn][i], 0.f) * w3v[tn];
            p[tm][i] = s;
        }
    }
    #pragma unroll
    for (int m = 1; m <= 8; m <<= 1)
        #pragma unroll
        for (int tm = 0; tm < 4; ++tm)
            #pragma unroll
            for (int i = 0; i < 4; ++i)
                p[tm][i] += __shfl_xor(p[tm][i], m);

    // ---- sigmoid -> exp -> softmax sum (logits in [0,1], no max-shift needed)
    float ee[4][4];
    float sloc = 0.f;
    #pragma unroll
    for (int tm = 0; tm < 4; ++tm)
        #pragma unroll
        for (int i = 0; i < 4; ++i) {
            const float sg = 1.f / (1.f + __expf(-p[tm][i]));
            const float ex = __expf(sg);
            ee[tm][i] = ex;
            sloc += ex;
        }
    sloc += __shfl_xor(sloc, 16);
    sloc += __shfl_xor(sloc, 32);
    const float rS = 1.f / sloc;

    if (q == 0) {
        #pragma unroll
        for (int tm = 0; tm < 4; ++tm)
            #pragma unroll
            for (int i = 0; i < 4; ++i)
                ws_w[combo][16 * tm + 4 * g + i] = ee[tm][i] * rS;
    }
    __syncthreads();

    // ---- weighted t-sum + hop-0 means from prefetched registers
    float a8[8], m8[8];
    #pragma unroll
    for (int k = 0; k < 8; ++k) { a8[k] = 0.f; m8[k] = 0.f; }
    #pragma unroll
    for (int it = 0; it < 8; ++it) {
        const float w = ws_w[combo][8 * it + grp];
        const v4u e = e0v[it];
        a8[0] += w * bflo(e[0]); a8[1] += w * bfhi(e[0]);
        a8[2] += w * bflo(e[1]); a8[3] += w * bfhi(e[1]);
        a8[4] += w * bflo(e[2]); a8[5] += w * bfhi(e[2]);
        a8[6] += w * bflo(e[3]); a8[7] += w * bfhi(e[3]);
    }
    #pragma unroll
    for (int it = 0; it < 4; ++it) {
        const v4u e = m0v[it];
        m8[0] += bflo(e[0]); m8[1] += bfhi(e[0]);
        m8[2] += bflo(e[1]); m8[3] += bfhi(e[1]);
        m8[4] += bflo(e[2]); m8[5] += bfhi(e[2]);
        m8[6] += bflo(e[3]); m8[7] += bfhi(e[3]);
    }
    #pragma unroll
    for (int m = 8; m <= 32; m <<= 1)
        #pragma unroll
        for (int k = 0; k < 8; ++k) {
            a8[k] += __shfl_xor(a8[k], m);
            m8[k] += __shfl_xor(m8[k], m);
        }
    if (lane < 8) {
        #pragma unroll
        for (int k = 0; k < 8; ++k) {
            att_s[combo][lane * 8 + k] = a8[k];
            mp[combo][lane * 8 + k]    = m8[k];
        }
    }
    __syncthreads();

    // ---- final combine + dot + sigmoid (one wave)
    if (threadIdx.x < 64) {
        const int j = lane;
        const float eu = att_s[0][j] + att_s[1][j] + (mp[0][j] + mp[1][j]) * (1.f / 64.f);
        const float evv = emb[(size_t)items[b] * 64 + j] + att_s[2][j] + att_s[3][j]
                        + (mp[2][j] + mp[3][j]) * (1.f / 64.f);
        float d = eu * evv;
        #pragma unroll
        for (int m = 1; m <= 32; m <<= 1) d += __shfl_xor(d, m);
        if (lane == 0) out[b] = 1.f / (1.f + __expf(-d));
    }
}

extern "C" void kernel_launch(void* const* d_in, const int* in_sizes, int n_in,
                              void* d_out, int out_size, void* d_ws, size_t ws_size,
                              hipStream_t stream)
{
    const int*   items  = (const int*)d_in[0];
    const int*   user_h = (const int*)d_in[1];
    const int*   user_r = (const int*)d_in[2];
    const int*   user_t = (const int*)d_in[3];
    const int*   item_h = (const int*)d_in[4];
    const int*   item_r = (const int*)d_in[5];
    const int*   item_t = (const int*)d_in[6];
    const float* emb    = (const float*)d_in[7];
    const float* rel    = (const float*)d_in[8];
    const float* W1     = (const float*)d_in[9];
    const float* W2     = (const float*)d_in[10];
    const float* W3     = (const float*)d_in[11];
    float* out = (float*)d_out;

    char* ws = (char*)d_ws;
    const size_t tb = (size_t)N_ENT * 64 * 2;           // 12.8 MB per table
    unsigned short* E0  = (unsigned short*)ws;
    unsigned short* E1  = (unsigned short*)(ws + tb);
    unsigned short* R1b = (unsigned short*)(ws + 2 * tb);
    unsigned short* W2p = (unsigned short*)(ws + 2 * tb + 4096);
    unsigned short* W1p = (unsigned short*)(ws + 2 * tb + 4096 + 8192);

    hipLaunchKernelGGL(k0_prep, dim3(40), dim3(256), 0, stream, rel, W1, W2, R1b, W2p, W1p);
    hipLaunchKernelGGL(k1_e1, dim3((6250 + 3) / 4), dim3(256), 0, stream, emb, W1p, E1, E0);
    hipLaunchKernelGGL(k2_fused, dim3(BATCH), dim3(256), 0, stream,
                       items, user_h, user_r, user_t, item_h, item_r, item_t,
                       emb, E0, E1, R1b, W2p, W3, out);
}